// Round 2
// baseline (2643.772 us; speedup 1.0000x reference)
//
#include <hip/hip_runtime.h>
#include <stdint.h>

#define U_N 100000
#define I_N 50000
#define D_DIM 64
#define E_N 6400000
#define B_N 16384
#define N_N 150000
#define LAYERS 3
#define NB 1024          // buckets
#define BKN 147          // nodes per bucket: ceil(150000/1024)

// ---------- init: emb0 = concat(user_emb, item_emb) ----------
__global__ __launch_bounds__(256) void init_emb(const float4* __restrict__ ue,
                                                const float4* __restrict__ ie,
                                                float4* __restrict__ emb) {
    const int n4 = N_N * D_DIM / 4;
    const int u4 = U_N * D_DIM / 4;
    for (int i = blockIdx.x * blockDim.x + threadIdx.x; i < n4;
         i += gridDim.x * blockDim.x) {
        emb[i] = (i < u4) ? ue[i] : ie[i - u4];
    }
}

// ---------- per-node histogram ----------
__global__ __launch_bounds__(256) void hist_node(const int* __restrict__ dst,
                                                 int* __restrict__ counts) {
    for (int e = blockIdx.x * blockDim.x + threadIdx.x; e < E_N;
         e += gridDim.x * blockDim.x) {
        atomicAdd(&counts[dst[e]], 1);
    }
}

// ---------- bucket totals: one wave per bucket ----------
__global__ __launch_bounds__(256) void bucket_tot(const int* __restrict__ counts,
                                                  int* __restrict__ btot) {
    int b = blockIdx.x * 4 + (threadIdx.x >> 6);
    int lane = threadIdx.x & 63;
    if (b >= NB) return;
    int sum = 0;
    for (int i = lane; i < BKN; i += 64) {
        int node = b * BKN + i;
        if (node < N_N) sum += counts[node];
    }
#pragma unroll
    for (int off = 32; off > 0; off >>= 1) sum += __shfl_xor(sum, off, 64);
    if (lane == 0) btot[b] = sum;
}

// ---------- exclusive scan of 1024 bucket totals (one block) ----------
__global__ __launch_bounds__(NB) void scan_buckets(const int* __restrict__ btot,
                                                   int* __restrict__ bbase,
                                                   int* __restrict__ bcur,
                                                   int* __restrict__ row_ptr) {
    __shared__ int lds[NB];
    int t = threadIdx.x;
    int x = btot[t];
    lds[t] = x;
    __syncthreads();
    for (int off = 1; off < NB; off <<= 1) {
        int v = (t >= off) ? lds[t - off] : 0;
        __syncthreads();
        lds[t] += v;
        __syncthreads();
    }
    int excl = lds[t] - x;
    bbase[t] = excl;
    bcur[t] = excl;
    if (t == NB - 1) {
        bbase[NB] = lds[NB - 1];
        row_ptr[N_N] = lds[NB - 1];   // == E
    }
}

// ---------- row_ptr: per-bucket wave scan ----------
__global__ __launch_bounds__(256) void row_ptr_build(const int* __restrict__ counts,
                                                     const int* __restrict__ bbase,
                                                     int* __restrict__ row_ptr) {
    int b = blockIdx.x * 4 + (threadIdx.x >> 6);
    int lane = threadIdx.x & 63;
    if (b >= NB) return;
    int base = bbase[b];
    int carry = 0;
    for (int c = 0; c < BKN; c += 64) {
        int i = c + lane;
        int node = b * BKN + i;
        int x = (i < BKN && node < N_N) ? counts[node] : 0;
        int inc = x;
#pragma unroll
        for (int off = 1; off < 64; off <<= 1) {
            int v = __shfl_up(inc, off, 64);
            if (lane >= off) inc += v;
        }
        if (i < BKN && node < N_N) row_ptr[node] = base + carry + (inc - x);
        carry += __shfl(inc, 63, 64);
    }
}

// ---------- phase A: bucket-partition edges, packed 8B records ----------
// record = val(32) | dst_local(8) @bit18 | src(18)
__global__ __launch_bounds__(256) void phaseA(const int* __restrict__ src,
                                              const int* __restrict__ dst,
                                              const float* __restrict__ vals,
                                              int* __restrict__ bcur,
                                              unsigned long long* __restrict__ staging) {
    for (int e = blockIdx.x * blockDim.x + threadIdx.x; e < E_N;
         e += gridDim.x * blockDim.x) {
        unsigned d = (unsigned)dst[e];
        unsigned b = d / BKN;             // magic-mul by compiler
        unsigned local = d - b * BKN;
        int pos = atomicAdd(&bcur[b], 1);
        unsigned long long rec = ((unsigned long long)__float_as_uint(vals[e]) << 32)
                               | ((unsigned long long)local << 18)
                               | (unsigned long long)(unsigned)src[e];
        staging[pos] = rec;
    }
}

// ---------- phase B: within-bucket scatter via LDS cursors ----------
__global__ __launch_bounds__(256) void phaseB(const unsigned long long* __restrict__ staging,
                                              const int* __restrict__ bbase,
                                              const int* __restrict__ row_ptr,
                                              int2* __restrict__ csr) {
    __shared__ int curs[BKN];
    int b = blockIdx.x;
    for (int i = threadIdx.x; i < BKN; i += 256) {
        int node = b * BKN + i;
        curs[i] = (node < N_N) ? row_ptr[node] : 0;
    }
    __syncthreads();
    int beg = bbase[b], end = bbase[b + 1];
    for (int e = beg + (int)threadIdx.x; e < end; e += 256) {
        unsigned long long rec = staging[e];
        int s = (int)(rec & 0x3FFFFull);
        int local = (int)((rec >> 18) & 0xFFull);
        int pos = atomicAdd(&curs[local], 1);
        csr[pos] = make_int2(s, (int)(rec >> 32));
    }
}

// ---------- fallback direct scatter (if ws too small for staging) ----------
__global__ __launch_bounds__(256) void copy_int(const int* __restrict__ in,
                                                int* __restrict__ out, int n) {
    for (int i = blockIdx.x * blockDim.x + threadIdx.x; i < n;
         i += gridDim.x * blockDim.x)
        out[i] = in[i];
}

__global__ __launch_bounds__(256) void scatter_direct(const int* __restrict__ src,
                                                      const int* __restrict__ dst,
                                                      const float* __restrict__ vals,
                                                      int* __restrict__ cursor,
                                                      int2* __restrict__ csr) {
    for (int e = blockIdx.x * blockDim.x + threadIdx.x; e < E_N;
         e += gridDim.x * blockDim.x) {
        int d = dst[e];
        int pos = atomicAdd(&cursor[d], 1);
        csr[pos] = make_int2(src[e], __float_as_int(vals[e]));
    }
}

// ---------- SpMM pull: one wave per row, batched record loads ----------
__global__ __launch_bounds__(256) void spmm_kernel(const float* __restrict__ ecur,
                                                   float* __restrict__ enext,
                                                   const int* __restrict__ row_ptr,
                                                   const int2* __restrict__ csr) {
    int row = blockIdx.x * 4 + (threadIdx.x >> 6);
    int lane = threadIdx.x & 63;
    if (row >= N_N) return;
    int beg = row_ptr[row];
    int end = row_ptr[row + 1];
    float acc = 0.0f;
    for (int base = beg; base < end; base += 64) {
        int2 rec = (base + lane < end) ? csr[base + lane] : make_int2(0, 0);
        int cnt = min(64, end - base);
        for (int j = 0; j < cnt; ++j) {
            int s = __shfl(rec.x, j, 64);
            float v = __int_as_float(__shfl(rec.y, j, 64));
            acc += v * ecur[(size_t)s * D_DIM + lane];
        }
    }
    enext[(size_t)row * D_DIM + lane] = acc;
}

// ---------- accumulate sampled rows into su/si ----------
__global__ __launch_bounds__(256) void accum_batch(const float* __restrict__ emb,
                                                   const int* __restrict__ users,
                                                   const int* __restrict__ items,
                                                   float* __restrict__ su,
                                                   float* __restrict__ si) {
    int r = blockIdx.x * 4 + (threadIdx.x >> 6);
    int lane = threadIdx.x & 63;
    if (r >= 2 * B_N) return;
    if (r < B_N) {
        int node = users[r];
        su[(size_t)r * D_DIM + lane] += emb[(size_t)node * D_DIM + lane];
    } else {
        int b = r - B_N;
        int node = U_N + items[b];
        si[(size_t)b * D_DIM + lane] += emb[(size_t)node * D_DIM + lane];
    }
}

// ---------- gamma = su.si/16 + 64*(ub+ib) ----------
__global__ __launch_bounds__(256) void gamma_kernel(const float* __restrict__ su,
                                                    const float* __restrict__ si,
                                                    const float* __restrict__ ub,
                                                    const float* __restrict__ ib,
                                                    const int* __restrict__ users,
                                                    const int* __restrict__ items,
                                                    float* __restrict__ out) {
    int b = blockIdx.x * 4 + (threadIdx.x >> 6);
    int lane = threadIdx.x & 63;
    if (b >= B_N) return;
    float p = su[(size_t)b * D_DIM + lane] * si[(size_t)b * D_DIM + lane];
#pragma unroll
    for (int off = 32; off > 0; off >>= 1) p += __shfl_xor(p, off, 64);
    if (lane == 0) {
        float bias = ub[users[b]] + ib[items[b]];
        out[b] = p * (1.0f / 16.0f) + 64.0f * bias;
    }
}

extern "C" void kernel_launch(void* const* d_in, const int* in_sizes, int n_in,
                              void* d_out, int out_size, void* d_ws, size_t ws_size,
                              hipStream_t stream) {
    const float* user_emb  = (const float*)d_in[0];
    const float* item_emb  = (const float*)d_in[1];
    const float* user_bias = (const float*)d_in[2];
    const float* item_bias = (const float*)d_in[3];
    const float* vals      = (const float*)d_in[4];
    const int*   src       = (const int*)d_in[5];
    const int*   dst       = (const int*)d_in[6];
    const int*   users     = (const int*)d_in[7];
    const int*   items     = (const int*)d_in[8];
    float* out = (float*)d_out;

    char* ws = (char*)d_ws;
    size_t off = 0;
    auto alloc = [&](size_t bytes) -> void* {
        void* p = ws + off;
        off += (bytes + 255) & ~(size_t)255;
        return p;
    };
    float* emb0    = (float*)alloc(sizeof(float) * (size_t)N_N * D_DIM);   // 38.4MB
    float* emb1    = (float*)alloc(sizeof(float) * (size_t)N_N * D_DIM);   // 38.4MB
    float* su      = (float*)alloc(sizeof(float) * (size_t)B_N * D_DIM);   // 4.2MB
    float* si      = (float*)alloc(sizeof(float) * (size_t)B_N * D_DIM);   // 4.2MB
    int*   counts  = (int*)alloc(sizeof(int) * N_N);                       // 0.6MB
    int*   row_ptr = (int*)alloc(sizeof(int) * (N_N + 1));                 // 0.6MB
    int*   bbase   = (int*)alloc(sizeof(int) * (NB + 1));
    int*   bcur    = (int*)alloc(sizeof(int) * NB);
    int2*  csr     = (int2*)alloc(sizeof(int2) * (size_t)E_N);             // 51.2MB
    size_t base_needed = off;
    unsigned long long* staging =
        (unsigned long long*)alloc(sizeof(unsigned long long) * (size_t)E_N); // 51.2MB
    size_t full_needed = off;
    bool use_bucketed = (ws_size >= full_needed);
    (void)base_needed;

    hipMemsetAsync(su, 0, sizeof(float) * (size_t)B_N * D_DIM * 2, stream);
    hipMemsetAsync(counts, 0, sizeof(int) * N_N, stream);

    init_emb<<<2048, 256, 0, stream>>>((const float4*)user_emb,
                                       (const float4*)item_emb, (float4*)emb0);
    hist_node<<<2048, 256, 0, stream>>>(dst, counts);
    bucket_tot<<<NB / 4, 256, 0, stream>>>(counts, bcur);      // bcur as temp btot
    scan_buckets<<<1, NB, 0, stream>>>(bcur, bbase, bcur, row_ptr);
    row_ptr_build<<<NB / 4, 256, 0, stream>>>(counts, bbase, row_ptr);

    if (use_bucketed) {
        phaseA<<<2048, 256, 0, stream>>>(src, dst, vals, bcur, staging);
        phaseB<<<NB, 256, 0, stream>>>(staging, bbase, row_ptr, csr);
    } else {
        copy_int<<<1024, 256, 0, stream>>>(row_ptr, counts, N_N);
        scatter_direct<<<2048, 256, 0, stream>>>(src, dst, vals, counts, csr);
    }

    // layer 0 contribution
    accum_batch<<<(2 * B_N) / 4, 256, 0, stream>>>(emb0, users, items, su, si);

    float* cur = emb0;
    float* nxt = emb1;
    for (int l = 0; l < LAYERS; ++l) {
        spmm_kernel<<<(N_N + 3) / 4, 256, 0, stream>>>(cur, nxt, row_ptr, csr);
        accum_batch<<<(2 * B_N) / 4, 256, 0, stream>>>(nxt, users, items, su, si);
        float* t = cur; cur = nxt; nxt = t;
    }

    gamma_kernel<<<B_N / 4, 256, 0, stream>>>(su, si, user_bias, item_bias,
                                              users, items, out);
}

// Round 3
// 1302.059 us; speedup vs baseline: 2.0305x; 2.0305x over previous
//
#include <hip/hip_runtime.h>
#include <stdint.h>

#define U_N 100000
#define I_N 50000
#define D_DIM 64
#define E_N 6400000
#define B_N 16384
#define N_N 150000
#define LAYERS 3
#define NB 1024          // buckets
#define BKN 147          // nodes per bucket: ceil(150000/1024)
#define CAP 8192         // phaseB LDS record capacity (64KB)

typedef unsigned long long ull;

// ---------- init: emb0 = concat(user_emb, item_emb) ----------
__global__ __launch_bounds__(256) void init_emb(const float4* __restrict__ ue,
                                                const float4* __restrict__ ie,
                                                float4* __restrict__ emb) {
    const int n4 = N_N * D_DIM / 4;
    const int u4 = U_N * D_DIM / 4;
    for (int i = blockIdx.x * blockDim.x + threadIdx.x; i < n4;
         i += gridDim.x * blockDim.x) {
        emb[i] = (i < u4) ? ue[i] : ie[i - u4];
    }
}

// ---------- bucket histogram, LDS-privatized ----------
__global__ __launch_bounds__(256) void bhist(const int* __restrict__ dst,
                                             int* __restrict__ btot) {
    __shared__ int h[NB];
    for (int i = threadIdx.x; i < NB; i += 256) h[i] = 0;
    __syncthreads();
    int chunk = (E_N + gridDim.x - 1) / gridDim.x;
    int beg = blockIdx.x * chunk;
    int end = min(E_N, beg + chunk);
    for (int e = beg + (int)threadIdx.x; e < end; e += 256)
        atomicAdd(&h[(unsigned)dst[e] / BKN], 1);
    __syncthreads();
    for (int i = threadIdx.x; i < NB; i += 256)
        if (h[i]) atomicAdd(&btot[i], h[i]);
}

// ---------- exclusive scan of 1024 bucket totals (one block) ----------
__global__ __launch_bounds__(NB) void scan_buckets(const int* __restrict__ btot,
                                                   int* __restrict__ bbase,
                                                   int* __restrict__ bcur,
                                                   int* __restrict__ row_ptr) {
    __shared__ int lds[NB];
    int t = threadIdx.x;
    int x = btot[t];
    lds[t] = x;
    __syncthreads();
    for (int off = 1; off < NB; off <<= 1) {
        int v = (t >= off) ? lds[t - off] : 0;
        __syncthreads();
        lds[t] += v;
        __syncthreads();
    }
    int excl = lds[t] - x;
    bbase[t] = excl;
    bcur[t] = excl;
    if (t == NB - 1) {
        bbase[NB] = lds[NB - 1];
        row_ptr[N_N] = lds[NB - 1];   // == E
    }
}

// ---------- phase A: block-privatized bucket partition ----------
// record = val(32) | dst_local(8) @bit18 | src(18)
__global__ __launch_bounds__(256) void phaseA(const int* __restrict__ src,
                                              const int* __restrict__ dst,
                                              const float* __restrict__ vals,
                                              int* __restrict__ bcur,
                                              ull* __restrict__ staging) {
    __shared__ int h[NB];
    __shared__ int base[NB];
    int chunk = (E_N + gridDim.x - 1) / gridDim.x;
    int beg = blockIdx.x * chunk;
    int end = min(E_N, beg + chunk);
    for (int i = threadIdx.x; i < NB; i += 256) h[i] = 0;
    __syncthreads();
    for (int e = beg + (int)threadIdx.x; e < end; e += 256)
        atomicAdd(&h[(unsigned)dst[e] / BKN], 1);
    __syncthreads();
    for (int i = threadIdx.x; i < NB; i += 256) {
        int c = h[i];
        base[i] = c ? atomicAdd(&bcur[i], c) : 0;
    }
    __syncthreads();
    for (int i = threadIdx.x; i < NB; i += 256) h[i] = 0;  // reuse as cursor
    __syncthreads();
    for (int e = beg + (int)threadIdx.x; e < end; e += 256) {
        unsigned d = (unsigned)dst[e];
        unsigned b = d / BKN;
        unsigned local = d - b * BKN;
        int pos = base[b] + atomicAdd(&h[b], 1);
        ull rec = ((ull)__float_as_uint(vals[e]) << 32)
                | ((ull)local << 18)
                | (ull)(unsigned)src[e];
        staging[pos] = rec;
    }
}

// ---------- phase B: one block per bucket; LDS-stage, sort, emit CSR+row_ptr ----------
__global__ __launch_bounds__(256) void phaseB(const ull* __restrict__ staging,
                                              const int* __restrict__ bbase,
                                              int2* __restrict__ csr,
                                              int* __restrict__ row_ptr) {
    __shared__ ull recs[CAP];
    __shared__ int hist[BKN];
    __shared__ int curs[BKN];
    int b = blockIdx.x;
    int beg = bbase[b];
    int cnt = bbase[b + 1] - beg;
    bool inlds = (cnt <= CAP);
    for (int i = threadIdx.x; i < BKN; i += 256) hist[i] = 0;
    __syncthreads();
    for (int i = threadIdx.x; i < cnt; i += 256) {
        ull rec = staging[beg + i];
        if (inlds) recs[i] = rec;
        atomicAdd(&hist[(int)((rec >> 18) & 0xFF)], 1);
    }
    __syncthreads();
    // wave 0: exclusive scan of 147 counts; write row_ptr + cursors
    if (threadIdx.x < 64) {
        int lane = threadIdx.x;
        int carry = 0;
        for (int c = 0; c < BKN; c += 64) {
            int i = c + lane;
            int x = (i < BKN) ? hist[i] : 0;
            int inc = x;
#pragma unroll
            for (int off = 1; off < 64; off <<= 1) {
                int v = __shfl_up(inc, off, 64);
                if (lane >= off) inc += v;
            }
            int excl = carry + inc - x;
            if (i < BKN) {
                int node = b * BKN + i;
                if (node < N_N) row_ptr[node] = beg + excl;
                curs[i] = excl;
            }
            carry += __shfl(inc, 63, 64);
        }
    }
    __syncthreads();
    for (int i = threadIdx.x; i < cnt; i += 256) {
        ull rec = inlds ? recs[i] : staging[beg + i];
        int local = (int)((rec >> 18) & 0xFF);
        int pos = atomicAdd(&curs[local], 1);
        csr[beg + pos] = make_int2((int)(rec & 0x3FFFFull), (int)(rec >> 32));
    }
}

// ---------- SpMM pull: one wave per row, batched record loads ----------
__global__ __launch_bounds__(256) void spmm_kernel(const float* __restrict__ ecur,
                                                   float* __restrict__ enext,
                                                   const int* __restrict__ row_ptr,
                                                   const int2* __restrict__ csr) {
    int row = blockIdx.x * 4 + (threadIdx.x >> 6);
    int lane = threadIdx.x & 63;
    if (row >= N_N) return;
    int beg = row_ptr[row];
    int end = row_ptr[row + 1];
    float acc = 0.0f;
    for (int base = beg; base < end; base += 64) {
        int2 rec = (base + lane < end) ? csr[base + lane] : make_int2(0, 0);
        int cnt = min(64, end - base);
        for (int j = 0; j < cnt; ++j) {
            int s = __shfl(rec.x, j, 64);
            float v = __int_as_float(__shfl(rec.y, j, 64));
            acc += v * ecur[(size_t)s * D_DIM + lane];
        }
    }
    enext[(size_t)row * D_DIM + lane] = acc;
}

// ---------- accumulate sampled rows into su/si ----------
__global__ __launch_bounds__(256) void accum_batch(const float* __restrict__ emb,
                                                   const int* __restrict__ users,
                                                   const int* __restrict__ items,
                                                   float* __restrict__ su,
                                                   float* __restrict__ si) {
    int r = blockIdx.x * 4 + (threadIdx.x >> 6);
    int lane = threadIdx.x & 63;
    if (r >= 2 * B_N) return;
    if (r < B_N) {
        int node = users[r];
        su[(size_t)r * D_DIM + lane] += emb[(size_t)node * D_DIM + lane];
    } else {
        int b = r - B_N;
        int node = U_N + items[b];
        si[(size_t)b * D_DIM + lane] += emb[(size_t)node * D_DIM + lane];
    }
}

// ---------- gamma = su.si/16 + 64*(ub+ib) ----------
__global__ __launch_bounds__(256) void gamma_kernel(const float* __restrict__ su,
                                                    const float* __restrict__ si,
                                                    const float* __restrict__ ub,
                                                    const float* __restrict__ ib,
                                                    const int* __restrict__ users,
                                                    const int* __restrict__ items,
                                                    float* __restrict__ out) {
    int b = blockIdx.x * 4 + (threadIdx.x >> 6);
    int lane = threadIdx.x & 63;
    if (b >= B_N) return;
    float p = su[(size_t)b * D_DIM + lane] * si[(size_t)b * D_DIM + lane];
#pragma unroll
    for (int off = 32; off > 0; off >>= 1) p += __shfl_xor(p, off, 64);
    if (lane == 0) {
        float bias = ub[users[b]] + ib[items[b]];
        out[b] = p * (1.0f / 16.0f) + 64.0f * bias;
    }
}

extern "C" void kernel_launch(void* const* d_in, const int* in_sizes, int n_in,
                              void* d_out, int out_size, void* d_ws, size_t ws_size,
                              hipStream_t stream) {
    const float* user_emb  = (const float*)d_in[0];
    const float* item_emb  = (const float*)d_in[1];
    const float* user_bias = (const float*)d_in[2];
    const float* item_bias = (const float*)d_in[3];
    const float* vals      = (const float*)d_in[4];
    const int*   src       = (const int*)d_in[5];
    const int*   dst       = (const int*)d_in[6];
    const int*   users     = (const int*)d_in[7];
    const int*   items     = (const int*)d_in[8];
    float* out = (float*)d_out;

    char* ws = (char*)d_ws;
    size_t off = 0;
    auto alloc = [&](size_t bytes) -> void* {
        void* p = ws + off;
        off += (bytes + 255) & ~(size_t)255;
        return p;
    };
    float* emb0    = (float*)alloc(sizeof(float) * (size_t)N_N * D_DIM);   // 38.4MB
    float* emb1    = (float*)alloc(sizeof(float) * (size_t)N_N * D_DIM);   // 38.4MB
    float* su      = (float*)alloc(sizeof(float) * (size_t)B_N * D_DIM);   // 4.2MB
    float* si      = (float*)alloc(sizeof(float) * (size_t)B_N * D_DIM);   // 4.2MB
    int*   row_ptr = (int*)alloc(sizeof(int) * (N_N + 1));                 // 0.6MB
    int*   btot    = (int*)alloc(sizeof(int) * NB);
    int*   bbase   = (int*)alloc(sizeof(int) * (NB + 1));
    int*   bcur    = (int*)alloc(sizeof(int) * NB);
    int2*  csr     = (int2*)alloc(sizeof(int2) * (size_t)E_N);             // 51.2MB
    ull*   staging = (ull*)alloc(sizeof(ull) * (size_t)E_N);               // 51.2MB

    hipMemsetAsync(su, 0, sizeof(float) * (size_t)B_N * D_DIM * 2, stream);
    hipMemsetAsync(btot, 0, sizeof(int) * NB, stream);

    init_emb<<<2048, 256, 0, stream>>>((const float4*)user_emb,
                                       (const float4*)item_emb, (float4*)emb0);
    bhist<<<512, 256, 0, stream>>>(dst, btot);
    scan_buckets<<<1, NB, 0, stream>>>(btot, bbase, bcur, row_ptr);
    phaseA<<<512, 256, 0, stream>>>(src, dst, vals, bcur, staging);
    phaseB<<<NB, 256, 0, stream>>>(staging, bbase, csr, row_ptr);

    // layer 0 contribution
    accum_batch<<<(2 * B_N) / 4, 256, 0, stream>>>(emb0, users, items, su, si);

    float* cur = emb0;
    float* nxt = emb1;
    for (int l = 0; l < LAYERS; ++l) {
        spmm_kernel<<<(N_N + 3) / 4, 256, 0, stream>>>(cur, nxt, row_ptr, csr);
        accum_batch<<<(2 * B_N) / 4, 256, 0, stream>>>(nxt, users, items, su, si);
        float* t = cur; cur = nxt; nxt = t;
    }

    gamma_kernel<<<B_N / 4, 256, 0, stream>>>(su, si, user_bias, item_bias,
                                              users, items, out);
}